// Round 2
// baseline (223.229 us; speedup 1.0000x reference)
//
#include <hip/hip_runtime.h>

// E8 lattice closest-point decode, one 8-float row per thread (grid-stride).
// E8 = D8 ∪ (D8 + 1/2). Decode both cosets, keep the nearer (ties -> coset 0).
// Bit-exactness notes:
//  - jnp.round == round-half-to-even == rintf (v_rndne_f32)
//  - jnp.argmax: first index of max -> forward scan, strict '>'
//  - distance sums use numpy's pairwise tree order; FMA contraction disabled
//  - coset-1 residual computed as x - (f1 + 0.5), matching the reference

__global__ __launch_bounds__(256) void e8_decode_kernel(
    const float* __restrict__ x, float* __restrict__ out, int nrows) {
  #pragma clang fp contract(off)
  int stride = gridDim.x * blockDim.x;
  for (int row = blockIdx.x * blockDim.x + threadIdx.x; row < nrows; row += stride) {
    const float4* xv = reinterpret_cast<const float4*>(x) + (size_t)row * 2;
    float4 a = xv[0];
    float4 b = xv[1];
    float xr[8] = {a.x, a.y, a.z, a.w, b.x, b.y, b.z, b.w};

    float c0[8], c1[8];

    // ---- coset 0: closest point of D8 to x ----
    {
      float f[8], d[8];
      float sum = 0.0f;
      float best = -1.0f, dworst = 0.0f;
      int worst = 0;
      #pragma unroll
      for (int i = 0; i < 8; ++i) {
        f[i] = rintf(xr[i]);
        d[i] = xr[i] - f[i];
        float ad = fabsf(d[i]);
        if (ad > best) { best = ad; worst = i; dworst = d[i]; }
        sum += f[i];
      }
      int odd = ((int)sum) & 1;
      float step = (dworst >= 0.0f) ? 1.0f : -1.0f;
      float adj = odd ? step : 0.0f;
      #pragma unroll
      for (int i = 0; i < 8; ++i) {
        c0[i] = (i == worst) ? (f[i] + adj) : f[i];
      }
    }

    // ---- coset 1: closest point of D8 to (x - 1/2), then + 1/2 ----
    {
      float f[8], d[8];
      float sum = 0.0f;
      float best = -1.0f, dworst = 0.0f;
      int worst = 0;
      #pragma unroll
      for (int i = 0; i < 8; ++i) {
        float y = xr[i] - 0.5f;
        f[i] = rintf(y);
        d[i] = y - f[i];
        float ad = fabsf(d[i]);
        if (ad > best) { best = ad; worst = i; dworst = d[i]; }
        sum += f[i];
      }
      int odd = ((int)sum) & 1;
      float step = (dworst >= 0.0f) ? 1.0f : -1.0f;
      float adj = odd ? step : 0.0f;
      #pragma unroll
      for (int i = 0; i < 8; ++i) {
        float fi = (i == worst) ? (f[i] + adj) : f[i];
        c1[i] = fi + 0.5f;   // exact: integer + 0.5 in fp32
      }
    }

    // ---- squared distances, numpy pairwise order, no FMA ----
    float q0[8], q1[8];
    #pragma unroll
    for (int i = 0; i < 8; ++i) {
      float r0 = xr[i] - c0[i];
      q0[i] = r0 * r0;
      float r1 = xr[i] - c1[i];
      q1[i] = r1 * r1;
    }
    float d0 = ((q0[0] + q0[1]) + (q0[2] + q0[3])) + ((q0[4] + q0[5]) + (q0[6] + q0[7]));
    float d1 = ((q1[0] + q1[1]) + (q1[2] + q1[3])) + ((q1[4] + q1[5]) + (q1[6] + q1[7]));

    bool pick0 = (d0 <= d1);
    float4 oa, ob;
    oa.x = pick0 ? c0[0] : c1[0];
    oa.y = pick0 ? c0[1] : c1[1];
    oa.z = pick0 ? c0[2] : c1[2];
    oa.w = pick0 ? c0[3] : c1[3];
    ob.x = pick0 ? c0[4] : c1[4];
    ob.y = pick0 ? c0[5] : c1[5];
    ob.z = pick0 ? c0[6] : c1[6];
    ob.w = pick0 ? c0[7] : c1[7];

    float4* ov = reinterpret_cast<float4*>(out) + (size_t)row * 2;
    ov[0] = oa;
    ov[1] = ob;
  }
}

extern "C" void kernel_launch(void* const* d_in, const int* in_sizes, int n_in,
                              void* d_out, int out_size, void* d_ws, size_t ws_size,
                              hipStream_t stream) {
  const float* x = (const float*)d_in[0];
  float* out = (float*)d_out;
  int nrows = in_sizes[0] / 8;
  int block = 256;
  int grid = (nrows + block - 1) / block;
  if (grid > 2048) grid = 2048;   // grid-stride covers the rest
  e8_decode_kernel<<<grid, block, 0, stream>>>(x, out, nrows);
}